// Round 1
// baseline (766.371 us; speedup 1.0000x reference)
//
#include <hip/hip_runtime.h>
#include <hip/hip_bf16.h>

#define VOCAB 50257
#define EMB 256
#define HID 256
#define BB 128
#define SS 2048

typedef __attribute__((ext_vector_type(8))) short short8;
typedef __attribute__((ext_vector_type(4))) float f32x4;

__device__ inline unsigned short f2bf(float f) {
    unsigned int u = __float_as_uint(f);
    u += 0x7FFFu + ((u >> 16) & 1u);
    return (unsigned short)(u >> 16);
}
__device__ inline unsigned int pack2(float a, float b) {
    return (unsigned int)f2bf(a) | ((unsigned int)f2bf(b) << 16);
}
__device__ inline uint4 pack8(float4 a, float4 b) {
    return make_uint4(pack2(a.x, a.y), pack2(a.z, a.w), pack2(b.x, b.y), pack2(b.z, b.w));
}

// ---------------------------------------------------------------------------
// K1: qb[b][h] = W1_b[h] + W2_b[h] + sum_k h0[b][k]*W2[h][k]   (blocks 0..127)
//     W1 fp32 -> bf16 [h][k]                                    (blocks 128..191)
// ---------------------------------------------------------------------------
__global__ __launch_bounds__(256) void k_prep(
    const float* __restrict__ hidden, const float* __restrict__ W2,
    const float* __restrict__ W1bias, const float* __restrict__ W2bias,
    const float* __restrict__ W1, unsigned short* __restrict__ W1bf,
    float* __restrict__ qb)
{
    const int bid = blockIdx.x, tid = threadIdx.x;
    if (bid < BB) {
        __shared__ float h0s[HID];
        h0s[tid] = hidden[bid * HID + tid];
        __syncthreads();
        const float4* w2r = (const float4*)(W2 + (size_t)tid * HID);
        float acc = W1bias[tid] + W2bias[tid];
        #pragma unroll 4
        for (int k4 = 0; k4 < HID / 4; ++k4) {
            float4 w = w2r[k4];
            acc += w.x * h0s[k4*4] + w.y * h0s[k4*4+1] + w.z * h0s[k4*4+2] + w.w * h0s[k4*4+3];
        }
        qb[bid * HID + tid] = acc;
    } else {
        int idx = (bid - BB) * 256 + tid;        // 16384 float4s total
        float4 v = ((const float4*)W1)[idx];
        ushort4 o;
        o.x = f2bf(v.x); o.y = f2bf(v.y); o.z = f2bf(v.z); o.w = f2bf(v.w);
        ((ushort4*)W1bf)[idx] = o;
    }
}

// ---------------------------------------------------------------------------
// K2: e[b][s] = V_b + sum_h V[h] * tanh( enc[s,b,:]@W1[h,:] + qb[b][h] )
// One block per s. Block tile 128(b) x 256(h), K=256, BK=32, MFMA 16x16x32 bf16.
// 4 waves in 2x2 grid; wave tile 64 x 128 (Mrep=4, Nrep=8).
// ---------------------------------------------------------------------------
__global__ __launch_bounds__(256, 2) void k_escore(
    const float* __restrict__ enc, const unsigned short* __restrict__ W1bf,
    const float* __restrict__ qb, const float* __restrict__ Vw,
    const float* __restrict__ Vb, float* __restrict__ e)
{
    __shared__ __align__(16) char As[128 * 64];   // 128 rows(b) x 32 k bf16, XOR-swizzled
    __shared__ __align__(16) char Bs[256 * 64];   // 256 cols(h) x 32 k bf16, XOR-swizzled
    __shared__ float esum[128];

    const int s = blockIdx.x;
    const int tid = threadIdx.x;
    const int lane = tid & 63, wid = tid >> 6;
    const int wm = wid >> 1, wn = wid & 1;
    const int lg = lane >> 4, li = lane & 15;

    if (tid < 128) esum[tid] = 0.f;

    f32x4 acc[4][8];
    #pragma unroll
    for (int m = 0; m < 4; ++m)
        #pragma unroll
        for (int n = 0; n < 8; ++n)
            acc[m][n] = (f32x4){0.f, 0.f, 0.f, 0.f};

    // staging maps
    const int arow = tid >> 1, ahalf = tid & 1;
    const float* aptr = enc + ((size_t)s * BB + arow) * HID + ahalf * 16;
    char* awr0 = As + arow * 64 + ((ahalf * 32)      ^ ((arow & 3) << 4));
    char* awr1 = As + arow * 64 + ((ahalf * 32 + 16) ^ ((arow & 3) << 4));
    const int bcol = tid; // h
    const unsigned short* bptr = W1bf + (size_t)bcol * HID;

    int a_off[4], b_off[8];
    #pragma unroll
    for (int m = 0; m < 4; ++m) { int r = wm*64 + m*16 + li; a_off[m] = r*64 + ((lg*16) ^ ((r&3)<<4)); }
    #pragma unroll
    for (int n = 0; n < 8; ++n) { int c = wn*128 + n*16 + li; b_off[n] = c*64 + ((lg*16) ^ ((c&3)<<4)); }

    for (int kt = 0; kt < 8; ++kt) {
        __syncthreads();
        // stage A (enc fp32 -> bf16)
        const float4* ap = (const float4*)(aptr + kt * 32);
        float4 f0 = ap[0], f1 = ap[1], f2 = ap[2], f3 = ap[3];
        *(uint4*)awr0 = pack8(f0, f1);
        *(uint4*)awr1 = pack8(f2, f3);
        // stage B (W1 bf16 copy, swizzled dest)
        const uint4* bp = (const uint4*)(bptr + kt * 32);
        #pragma unroll
        for (int slot = 0; slot < 4; ++slot)
            *(uint4*)(Bs + bcol * 64 + ((slot * 16) ^ ((bcol & 3) << 4))) = bp[slot];
        __syncthreads();
        // compute
        short8 a[4];
        #pragma unroll
        for (int m = 0; m < 4; ++m) a[m] = *(const short8*)(As + a_off[m]);
        #pragma unroll
        for (int n = 0; n < 8; ++n) {
            short8 b = *(const short8*)(Bs + b_off[n]);
            #pragma unroll
            for (int m = 0; m < 4; ++m)
                acc[m][n] = __builtin_amdgcn_mfma_f32_16x16x32_bf16(a[m], b, acc[m][n], 0, 0, 0);
        }
    }

    // epilogue: p(row) = sum_h V[h]*tanh(acc + qb[row][h]); reduce over 16 lanes
    #pragma unroll
    for (int m = 0; m < 4; ++m) {
        #pragma unroll
        for (int r = 0; r < 4; ++r) {
            const int brow = wm*64 + m*16 + lg*4 + r;
            float p = 0.f;
            #pragma unroll
            for (int n = 0; n < 8; ++n) {
                const int h = wn*128 + n*16 + li;
                float v = acc[m][n][r] + qb[brow * HID + h];
                p += Vw[h] * tanhf(v);
            }
            p += __shfl_xor(p, 1); p += __shfl_xor(p, 2);
            p += __shfl_xor(p, 4); p += __shfl_xor(p, 8);
            if (li == 0) atomicAdd(&esum[brow], p);
        }
    }
    __syncthreads();
    if (tid < 128) e[(size_t)tid * SS + s] = esum[tid] + Vb[0];
}

// ---------------------------------------------------------------------------
// K3: softmax over s per b; writes attw [b][s] into d_out
// ---------------------------------------------------------------------------
__global__ __launch_bounds__(256) void k_softmax(
    const float* __restrict__ e, float* __restrict__ attw)
{
    __shared__ float redm[4];
    __shared__ float reds[4];
    const int b = blockIdx.x, tid = threadIdx.x;
    const float* er = e + (size_t)b * SS;
    float v[8];
    float m = -1e30f;
    #pragma unroll
    for (int i = 0; i < 8; ++i) { v[i] = er[tid + i * 256]; m = fmaxf(m, v[i]); }
    #pragma unroll
    for (int off = 1; off < 64; off <<= 1) m = fmaxf(m, __shfl_xor(m, off));
    if ((tid & 63) == 0) redm[tid >> 6] = m;
    __syncthreads();
    m = fmaxf(fmaxf(redm[0], redm[1]), fmaxf(redm[2], redm[3]));
    float sum = 0.f;
    #pragma unroll
    for (int i = 0; i < 8; ++i) { v[i] = __expf(v[i] - m); sum += v[i]; }
    #pragma unroll
    for (int off = 1; off < 64; off <<= 1) sum += __shfl_xor(sum, off);
    if ((tid & 63) == 0) reds[tid >> 6] = sum;
    __syncthreads();
    const float inv = 1.f / (reds[0] + reds[1] + reds[2] + reds[3]);
    float* aw = attw + (size_t)b * SS;
    #pragma unroll
    for (int i = 0; i < 8; ++i) aw[tid + i * 256] = v[i] * inv;
}

// ---------------------------------------------------------------------------
// K4: ctx[b][h] += sum_{s in chunk} attw[b][s] * enc[s][b][h]
// grid = 128 b * 8 chunks of 256 s
// ---------------------------------------------------------------------------
__global__ __launch_bounds__(256) void k_ctx(
    const float* __restrict__ enc, const float* __restrict__ attw,
    float* __restrict__ ctx)
{
    __shared__ float aws[256];
    const int b = blockIdx.x >> 3, chunk = blockIdx.x & 7, tid = threadIdx.x;
    const int s0 = chunk * 256;
    aws[tid] = attw[(size_t)b * SS + s0 + tid];
    __syncthreads();
    float acc = 0.f;
    const float* ep = enc + ((size_t)s0 * BB + b) * HID + tid;
    #pragma unroll 4
    for (int i = 0; i < 256; ++i)
        acc += aws[i] * ep[(size_t)i * BB * HID];
    atomicAdd(&ctx[b * HID + tid], acc);
}

// ---------------------------------------------------------------------------
// K5: LSTM step (fp32 exact). One block per b.
// ---------------------------------------------------------------------------
__global__ __launch_bounds__(256) void k_lstm(
    const float* __restrict__ ctx, const int* __restrict__ x,
    const float* __restrict__ emb_table, const float* __restrict__ hidden,
    const float* __restrict__ cell,
    const float* __restrict__ W_ih, const float* __restrict__ W_hh,
    const float* __restrict__ b_ih, const float* __restrict__ b_hh,
    float* __restrict__ out_h, float* __restrict__ out_c)
{
    __shared__ float rin[768];     // [ctx | emb | h0]
    __shared__ float gates[1024];
    const int b = blockIdx.x, tid = threadIdx.x;
    rin[tid]       = ctx[b * HID + tid];
    rin[256 + tid] = emb_table[(size_t)x[b] * EMB + tid];
    rin[512 + tid] = hidden[b * HID + tid];
    __syncthreads();
    #pragma unroll
    for (int jj = 0; jj < 4; ++jj) {
        const int j = jj * 256 + tid;
        float acc = b_ih[j] + b_hh[j];
        const float4* wi = (const float4*)(W_ih + (size_t)j * 512);
        #pragma unroll 4
        for (int k4 = 0; k4 < 128; ++k4) {
            float4 w = wi[k4];
            acc += w.x*rin[k4*4] + w.y*rin[k4*4+1] + w.z*rin[k4*4+2] + w.w*rin[k4*4+3];
        }
        const float4* wh = (const float4*)(W_hh + (size_t)j * 256);
        #pragma unroll 4
        for (int k4 = 0; k4 < 64; ++k4) {
            float4 w = wh[k4];
            acc += w.x*rin[512+k4*4] + w.y*rin[512+k4*4+1] + w.z*rin[512+k4*4+2] + w.w*rin[512+k4*4+3];
        }
        gates[j] = acc;
    }
    __syncthreads();
    const float ig = gates[tid], fg = gates[256 + tid];
    const float gg = gates[512 + tid], og = gates[768 + tid];
    const float c0 = cell[b * HID + tid];
    const float si = 1.f / (1.f + __expf(-ig));
    const float sf = 1.f / (1.f + __expf(-fg));
    const float so = 1.f / (1.f + __expf(-og));
    const float cn = sf * c0 + si * tanhf(gg);
    const float hn = so * tanhf(cn);
    out_c[b * HID + tid] = cn;
    out_h[b * HID + tid] = hn;
}

// ---------------------------------------------------------------------------
// K6: predictions[b][v] = h_new[b,:]@fc_w[v,:] + fc_b[v]
// Block tile 128(b) x 128(v), K=256, BK=32, MFMA bf16. Grid 393.
// ---------------------------------------------------------------------------
__global__ __launch_bounds__(256, 2) void k_fc(
    const float* __restrict__ hnew, const float* __restrict__ fcw,
    const float* __restrict__ fcb, float* __restrict__ pred)
{
    __shared__ __align__(16) char As[128 * 64];
    __shared__ __align__(16) char Bs[128 * 64];
    const int vbase = blockIdx.x * 128;
    const int tid = threadIdx.x;
    const int lane = tid & 63, wid = tid >> 6;
    const int wm = wid >> 1, wn = wid & 1;
    const int lg = lane >> 4, li = lane & 15;

    f32x4 acc[4][4];
    #pragma unroll
    for (int m = 0; m < 4; ++m)
        #pragma unroll
        for (int n = 0; n < 4; ++n)
            acc[m][n] = (f32x4){0.f, 0.f, 0.f, 0.f};

    const int arow = tid >> 1, ahalf = tid & 1;
    const float* aptr = hnew + (size_t)arow * HID + ahalf * 16;
    char* awr0 = As + arow * 64 + ((ahalf * 32)      ^ ((arow & 3) << 4));
    char* awr1 = As + arow * 64 + ((ahalf * 32 + 16) ^ ((arow & 3) << 4));
    const int bcol = arow;                 // local v col 0..127
    const int v = vbase + bcol;
    const bool vok = v < VOCAB;
    const float* bptr = fcw + (size_t)v * HID + ahalf * 16;
    char* bwr0 = Bs + bcol * 64 + ((ahalf * 32)      ^ ((bcol & 3) << 4));
    char* bwr1 = Bs + bcol * 64 + ((ahalf * 32 + 16) ^ ((bcol & 3) << 4));

    int a_off[4], b_off[4];
    #pragma unroll
    for (int m = 0; m < 4; ++m) { int r = wm*64 + m*16 + li; a_off[m] = r*64 + ((lg*16) ^ ((r&3)<<4)); }
    #pragma unroll
    for (int n = 0; n < 4; ++n) { int c = wn*64 + n*16 + li; b_off[n] = c*64 + ((lg*16) ^ ((c&3)<<4)); }

    for (int kt = 0; kt < 8; ++kt) {
        __syncthreads();
        const float4* ap = (const float4*)(aptr + kt * 32);
        float4 f0 = ap[0], f1 = ap[1], f2 = ap[2], f3 = ap[3];
        *(uint4*)awr0 = pack8(f0, f1);
        *(uint4*)awr1 = pack8(f2, f3);
        float4 g0, g1, g2, g3;
        if (vok) {
            const float4* bp = (const float4*)(bptr + kt * 32);
            g0 = bp[0]; g1 = bp[1]; g2 = bp[2]; g3 = bp[3];
        } else {
            g0 = g1 = g2 = g3 = make_float4(0.f, 0.f, 0.f, 0.f);
        }
        *(uint4*)bwr0 = pack8(g0, g1);
        *(uint4*)bwr1 = pack8(g2, g3);
        __syncthreads();
        short8 a[4];
        #pragma unroll
        for (int m = 0; m < 4; ++m) a[m] = *(const short8*)(As + a_off[m]);
        #pragma unroll
        for (int n = 0; n < 4; ++n) {
            short8 b = *(const short8*)(Bs + b_off[n]);
            #pragma unroll
            for (int m = 0; m < 4; ++m)
                acc[m][n] = __builtin_amdgcn_mfma_f32_16x16x32_bf16(a[m], b, acc[m][n], 0, 0, 0);
        }
    }

    #pragma unroll
    for (int m = 0; m < 4; ++m)
        #pragma unroll
        for (int r = 0; r < 4; ++r) {
            const int row = wm*64 + m*16 + lg*4 + r;
            #pragma unroll
            for (int n = 0; n < 4; ++n) {
                const int col = vbase + wn*64 + n*16 + li;
                if (col < VOCAB)
                    pred[(size_t)row * VOCAB + col] = acc[m][n][r] + fcb[col];
            }
        }
}

// ---------------------------------------------------------------------------
extern "C" void kernel_launch(void* const* d_in, const int* in_sizes, int n_in,
                              void* d_out, int out_size, void* d_ws, size_t ws_size,
                              hipStream_t stream)
{
    const int*   x      = (const int*)  d_in[0];
    const float* enc    = (const float*)d_in[1];
    const float* hidden = (const float*)d_in[2];
    const float* cell   = (const float*)d_in[3];
    const float* emb    = (const float*)d_in[4];
    const float* W_ih   = (const float*)d_in[5];
    const float* W_hh   = (const float*)d_in[6];
    const float* b_ih   = (const float*)d_in[7];
    const float* b_hh   = (const float*)d_in[8];
    const float* fc_w   = (const float*)d_in[9];
    const float* fc_b   = (const float*)d_in[10];
    const float* W1_w   = (const float*)d_in[11];
    const float* W1_b   = (const float*)d_in[12];
    const float* W2_w   = (const float*)d_in[13];
    const float* W2_b   = (const float*)d_in[14];
    const float* V_w    = (const float*)d_in[15];
    const float* V_b    = (const float*)d_in[16];

    float* out   = (float*)d_out;
    float* pred  = out;                                   // [128][50257]
    float* out_h = out + (size_t)BB * VOCAB;              // [128][256]
    float* out_c = out_h + BB * HID;                      // [128][256]
    float* attw  = out_c + BB * HID;                      // [128][2048]

    char* ws = (char*)d_ws;
    unsigned short* W1bf = (unsigned short*)ws;           // 131072 B
    float* qb  = (float*)(ws + 131072);                   // 131072 B
    float* e   = (float*)(ws + 262144);                   // 1 MiB
    float* ctx = (float*)(ws + 262144 + 1048576);         // 131072 B

    k_prep   <<<dim3(192),              dim3(256), 0, stream>>>(hidden, W2_w, W1_b, W2_b, W1_w, W1bf, qb);
    k_escore <<<dim3(SS),               dim3(256), 0, stream>>>(enc, W1bf, qb, V_w, V_b, e);
    k_softmax<<<dim3(BB),               dim3(256), 0, stream>>>(e, attw);
    hipMemsetAsync(ctx, 0, BB * HID * sizeof(float), stream);
    k_ctx    <<<dim3(BB * 8),           dim3(256), 0, stream>>>(enc, attw, ctx);
    k_lstm   <<<dim3(BB),               dim3(256), 0, stream>>>(ctx, x, emb, hidden, cell,
                                                                W_ih, W_hh, b_ih, b_hh, out_h, out_c);
    k_fc     <<<dim3((VOCAB + 127)/128), dim3(256), 0, stream>>>(out_h, fc_w, fc_b, pred);
}

// Round 2
// 682.509 us; speedup vs baseline: 1.1229x; 1.1229x over previous
//
#include <hip/hip_runtime.h>
#include <hip/hip_bf16.h>

#define VOCAB 50257
#define EMB 256
#define HID 256
#define BB 128
#define SS 2048

typedef __attribute__((ext_vector_type(8))) short short8;
typedef __attribute__((ext_vector_type(4))) float f32x4;

__device__ inline unsigned short f2bf(float f) {
    unsigned int u = __float_as_uint(f);
    u += 0x7FFFu + ((u >> 16) & 1u);
    return (unsigned short)(u >> 16);
}
__device__ inline unsigned int pack2(float a, float b) {
    return (unsigned int)f2bf(a) | ((unsigned int)f2bf(b) << 16);
}
__device__ inline uint4 pack8(float4 a, float4 b) {
    return make_uint4(pack2(a.x, a.y), pack2(a.z, a.w), pack2(b.x, b.y), pack2(b.z, b.w));
}
__device__ inline float fast_tanh(float x) {
    x = fminf(fmaxf(x, -9.f), 9.f);
    float t = __expf(2.f * x);
    return (t - 1.f) * __builtin_amdgcn_rcpf(t + 1.f);
}

// ---------------------------------------------------------------------------
// K1: qb[b][h] = W1_b[h] + W2_b[h] + sum_k h0[b][k]*W2[h][k]   (blocks 0..127)
//     W1 fp32 -> bf16 [h][k]                                    (blocks 128..191)
// ---------------------------------------------------------------------------
__global__ __launch_bounds__(256) void k_prep(
    const float* __restrict__ hidden, const float* __restrict__ W2,
    const float* __restrict__ W1bias, const float* __restrict__ W2bias,
    const float* __restrict__ W1, unsigned short* __restrict__ W1bf,
    float* __restrict__ qb)
{
    const int bid = blockIdx.x, tid = threadIdx.x;
    if (bid < BB) {
        __shared__ float h0s[HID];
        h0s[tid] = hidden[bid * HID + tid];
        __syncthreads();
        const float4* w2r = (const float4*)(W2 + (size_t)tid * HID);
        float acc = W1bias[tid] + W2bias[tid];
        #pragma unroll 4
        for (int k4 = 0; k4 < HID / 4; ++k4) {
            float4 w = w2r[k4];
            acc += w.x * h0s[k4*4] + w.y * h0s[k4*4+1] + w.z * h0s[k4*4+2] + w.w * h0s[k4*4+3];
        }
        qb[bid * HID + tid] = acc;
    } else {
        int idx = (bid - BB) * 256 + tid;        // 16384 float4s total
        float4 v = ((const float4*)W1)[idx];
        ushort4 o;
        o.x = f2bf(v.x); o.y = f2bf(v.y); o.z = f2bf(v.z); o.w = f2bf(v.w);
        ((ushort4*)W1bf)[idx] = o;
    }
}

// ---------------------------------------------------------------------------
// K2: e[b][s] = V_b + sum_h V[h] * tanh( enc_flat[r,:]@W1[h,:] + qb[b][h] )
// enc viewed as [S*B, 256] row-major (r = s*128 + b).
// Block tile: BM=256 rows x BN=256 h, K=256, BK=64. 512 thr / 8 waves (4x2).
// Wave tile 64 x 128: Mrep=4, Nrep=8, 2 k-slices -> 64 MFMA/wave/kt.
// ---------------------------------------------------------------------------
__global__ __launch_bounds__(512, 2) void k_escore(
    const float* __restrict__ enc, const unsigned short* __restrict__ W1bf,
    const float* __restrict__ qb, const float* __restrict__ Vw,
    const float* __restrict__ Vb, float* __restrict__ e)
{
    __shared__ __align__(16) char As[256 * 128];   // 256 rows x 64 k bf16, swizzled
    __shared__ __align__(16) char Bs[256 * 128];   // 256 cols x 64 k bf16, swizzled
    __shared__ float esum[256];

    const int tid = threadIdx.x;
    const int lane = tid & 63, wid = tid >> 6;
    const int wm = wid >> 1, wn = wid & 1;         // 4 x 2 wave grid
    const int lg = lane >> 4, li = lane & 15;
    const size_t row0 = (size_t)blockIdx.x * 256;

    if (tid < 256) esum[tid] = 0.f;

    f32x4 acc[4][8];
    #pragma unroll
    for (int m = 0; m < 4; ++m)
        #pragma unroll
        for (int n = 0; n < 8; ++n)
            acc[m][n] = (f32x4){0.f, 0.f, 0.f, 0.f};

    // A staging map: 16 lanes per row, 32 rows per pass, 8 passes
    const int a_k16 = tid & 15, a_row0 = tid >> 4;
    // B staging map: 8 lanes per col, 64 cols per pass, 4 passes
    const int b_k8 = tid & 7, b_col0 = tid >> 3;

    for (int kt = 0; kt < 4; ++kt) {
        __syncthreads();
        // stage A: enc fp32 -> bf16, coalesced 256B/row chunks
        #pragma unroll
        for (int i = 0; i < 8; ++i) {
            const int row = a_row0 + 32 * i;
            float4 v = *((const float4*)(enc + (row0 + row) * HID + kt * 64) + a_k16);
            uint2 p = make_uint2(pack2(v.x, v.y), pack2(v.z, v.w));
            *(uint2*)(As + row * 128 + ((a_k16 * 8) ^ ((row & 7) << 4))) = p;
        }
        // stage B: W1bf bf16 copy, swizzled dest
        #pragma unroll
        for (int i = 0; i < 4; ++i) {
            const int col = b_col0 + 64 * i;
            uint4 v = *((const uint4*)(W1bf + (size_t)col * HID + kt * 64) + b_k8);
            *(uint4*)(Bs + col * 128 + ((b_k8 * 16) ^ ((col & 7) << 4))) = v;
        }
        __syncthreads();
        // compute: 2 k-slices x (4m x 8n)
        #pragma unroll
        for (int ks = 0; ks < 2; ++ks) {
            short8 a[4];
            #pragma unroll
            for (int m = 0; m < 4; ++m) {
                const int r = wm * 64 + m * 16 + li;
                a[m] = *(const short8*)(As + r * 128 + ((ks * 64 + lg * 16) ^ ((r & 7) << 4)));
            }
            #pragma unroll
            for (int n = 0; n < 8; ++n) {
                const int c = wn * 128 + n * 16 + li;
                short8 b = *(const short8*)(Bs + c * 128 + ((ks * 64 + lg * 16) ^ ((c & 7) << 4)));
                #pragma unroll
                for (int m = 0; m < 4; ++m)
                    acc[m][n] = __builtin_amdgcn_mfma_f32_16x16x32_bf16(a[m], b, acc[m][n], 0, 0, 0);
            }
        }
    }

    // epilogue: p(row) = sum_h V[h]*tanh(acc + qb[b(row)][h]); reduce 16 lanes
    float vw[8];
    #pragma unroll
    for (int n = 0; n < 8; ++n) vw[n] = Vw[wn * 128 + n * 16 + li];

    #pragma unroll
    for (int m = 0; m < 4; ++m) {
        #pragma unroll
        for (int r = 0; r < 4; ++r) {
            const int lrow = wm * 64 + m * 16 + lg * 4 + r;
            const size_t g = row0 + lrow;
            const float* qbrow = qb + (size_t)(g & 127) * HID;
            float p = 0.f;
            #pragma unroll
            for (int n = 0; n < 8; ++n) {
                const int h = wn * 128 + n * 16 + li;
                p += vw[n] * fast_tanh(acc[m][n][r] + qbrow[h]);
            }
            p += __shfl_xor(p, 1); p += __shfl_xor(p, 2);
            p += __shfl_xor(p, 4); p += __shfl_xor(p, 8);
            if (li == 0) atomicAdd(&esum[lrow], p);
        }
    }
    __syncthreads();
    if (tid < 256) {
        const size_t g = row0 + tid;
        e[(size_t)(g & 127) * SS + (g >> 7)] = esum[tid] + Vb[0];
    }
}

// ---------------------------------------------------------------------------
// K3: softmax over s per b; writes attw [b][s] into d_out
// ---------------------------------------------------------------------------
__global__ __launch_bounds__(256) void k_softmax(
    const float* __restrict__ e, float* __restrict__ attw)
{
    __shared__ float redm[4];
    __shared__ float reds[4];
    const int b = blockIdx.x, tid = threadIdx.x;
    const float* er = e + (size_t)b * SS;
    float v[8];
    float m = -1e30f;
    #pragma unroll
    for (int i = 0; i < 8; ++i) { v[i] = er[tid + i * 256]; m = fmaxf(m, v[i]); }
    #pragma unroll
    for (int off = 1; off < 64; off <<= 1) m = fmaxf(m, __shfl_xor(m, off));
    if ((tid & 63) == 0) redm[tid >> 6] = m;
    __syncthreads();
    m = fmaxf(fmaxf(redm[0], redm[1]), fmaxf(redm[2], redm[3]));
    float sum = 0.f;
    #pragma unroll
    for (int i = 0; i < 8; ++i) { v[i] = __expf(v[i] - m); sum += v[i]; }
    #pragma unroll
    for (int off = 1; off < 64; off <<= 1) sum += __shfl_xor(sum, off);
    if ((tid & 63) == 0) reds[tid >> 6] = sum;
    __syncthreads();
    const float inv = 1.f / (reds[0] + reds[1] + reds[2] + reds[3]);
    float* aw = attw + (size_t)b * SS;
    #pragma unroll
    for (int i = 0; i < 8; ++i) aw[tid + i * 256] = v[i] * inv;
}

// ---------------------------------------------------------------------------
// K4: ctx[b][h] += sum_{s in chunk} attw[b][s] * enc[s][b][h]
// grid = 128 b * 8 chunks of 256 s. float4 loads, 4-way s-parallel per thread.
// ---------------------------------------------------------------------------
__global__ __launch_bounds__(256) void k_ctx(
    const float* __restrict__ enc, const float* __restrict__ attw,
    float* __restrict__ ctx)
{
    __shared__ float aws[256];
    __shared__ f32x4 red[256];
    const int b = blockIdx.x >> 3, chunk = blockIdx.x & 7, tid = threadIdx.x;
    const int s0 = chunk * 256;
    const int hq = tid & 63, sg = tid >> 6;
    aws[tid] = attw[(size_t)b * SS + s0 + tid];
    __syncthreads();
    const f32x4* base = (const f32x4*)enc + ((size_t)s0 * BB + b) * 64 + hq;
    f32x4 acc = (f32x4){0.f, 0.f, 0.f, 0.f};
    #pragma unroll 8
    for (int i = 0; i < 64; ++i) {
        const int sl = sg + i * 4;
        f32x4 v = base[(size_t)sl * (BB * HID / 4)];
        acc += v * aws[sl];
    }
    red[tid] = acc;
    __syncthreads();
    if (tid < 64) {
        f32x4 r = red[tid] + red[tid + 64] + red[tid + 128] + red[tid + 192];
        #pragma unroll
        for (int j = 0; j < 4; ++j)
            atomicAdd(&ctx[b * HID + tid * 4 + j], r[j]);
    }
}

// ---------------------------------------------------------------------------
// K5: LSTM step (fp32 exact). One block per b.
// ---------------------------------------------------------------------------
__global__ __launch_bounds__(256) void k_lstm(
    const float* __restrict__ ctx, const int* __restrict__ x,
    const float* __restrict__ emb_table, const float* __restrict__ hidden,
    const float* __restrict__ cell,
    const float* __restrict__ W_ih, const float* __restrict__ W_hh,
    const float* __restrict__ b_ih, const float* __restrict__ b_hh,
    float* __restrict__ out_h, float* __restrict__ out_c)
{
    __shared__ float rin[768];     // [ctx | emb | h0]
    __shared__ float gates[1024];
    const int b = blockIdx.x, tid = threadIdx.x;
    rin[tid]       = ctx[b * HID + tid];
    rin[256 + tid] = emb_table[(size_t)x[b] * EMB + tid];
    rin[512 + tid] = hidden[b * HID + tid];
    __syncthreads();
    #pragma unroll
    for (int jj = 0; jj < 4; ++jj) {
        const int j = jj * 256 + tid;
        float acc = b_ih[j] + b_hh[j];
        const float4* wi = (const float4*)(W_ih + (size_t)j * 512);
        #pragma unroll 4
        for (int k4 = 0; k4 < 128; ++k4) {
            float4 w = wi[k4];
            acc += w.x*rin[k4*4] + w.y*rin[k4*4+1] + w.z*rin[k4*4+2] + w.w*rin[k4*4+3];
        }
        const float4* wh = (const float4*)(W_hh + (size_t)j * 256);
        #pragma unroll 4
        for (int k4 = 0; k4 < 64; ++k4) {
            float4 w = wh[k4];
            acc += w.x*rin[512+k4*4] + w.y*rin[512+k4*4+1] + w.z*rin[512+k4*4+2] + w.w*rin[512+k4*4+3];
        }
        gates[j] = acc;
    }
    __syncthreads();
    const float ig = gates[tid], fg = gates[256 + tid];
    const float gg = gates[512 + tid], og = gates[768 + tid];
    const float c0 = cell[b * HID + tid];
    const float si = 1.f / (1.f + __expf(-ig));
    const float sf = 1.f / (1.f + __expf(-fg));
    const float so = 1.f / (1.f + __expf(-og));
    const float cn = sf * c0 + si * tanhf(gg);
    const float hn = so * tanhf(cn);
    out_c[b * HID + tid] = cn;
    out_h[b * HID + tid] = hn;
}

// ---------------------------------------------------------------------------
// K6: predictions[b][v] = h_new[b,:]@fc_w[v,:] + fc_b[v]
// Block tile 128(b) x 128(v), K=256, BK=32, MFMA bf16. Grid 393.
// ---------------------------------------------------------------------------
__global__ __launch_bounds__(256, 2) void k_fc(
    const float* __restrict__ hnew, const float* __restrict__ fcw,
    const float* __restrict__ fcb, float* __restrict__ pred)
{
    __shared__ __align__(16) char As[128 * 64];
    __shared__ __align__(16) char Bs[128 * 64];
    const int vbase = blockIdx.x * 128;
    const int tid = threadIdx.x;
    const int lane = tid & 63, wid = tid >> 6;
    const int wm = wid >> 1, wn = wid & 1;
    const int lg = lane >> 4, li = lane & 15;

    f32x4 acc[4][4];
    #pragma unroll
    for (int m = 0; m < 4; ++m)
        #pragma unroll
        for (int n = 0; n < 4; ++n)
            acc[m][n] = (f32x4){0.f, 0.f, 0.f, 0.f};

    const int arow = tid >> 1, ahalf = tid & 1;
    const float* aptr = hnew + (size_t)arow * HID + ahalf * 16;
    char* awr0 = As + arow * 64 + ((ahalf * 32)      ^ ((arow & 3) << 4));
    char* awr1 = As + arow * 64 + ((ahalf * 32 + 16) ^ ((arow & 3) << 4));
    const int bcol = arow;                 // local v col 0..127
    const int v = vbase + bcol;
    const bool vok = v < VOCAB;
    const float* bptr = fcw + (size_t)v * HID + ahalf * 16;
    char* bwr0 = Bs + bcol * 64 + ((ahalf * 32)      ^ ((bcol & 3) << 4));
    char* bwr1 = Bs + bcol * 64 + ((ahalf * 32 + 16) ^ ((bcol & 3) << 4));

    int a_off[4], b_off[4];
    #pragma unroll
    for (int m = 0; m < 4; ++m) { int r = wm*64 + m*16 + li; a_off[m] = r*64 + ((lg*16) ^ ((r&3)<<4)); }
    #pragma unroll
    for (int n = 0; n < 4; ++n) { int c = wn*64 + n*16 + li; b_off[n] = c*64 + ((lg*16) ^ ((c&3)<<4)); }

    for (int kt = 0; kt < 8; ++kt) {
        __syncthreads();
        const float4* ap = (const float4*)(aptr + kt * 32);
        float4 f0 = ap[0], f1 = ap[1], f2 = ap[2], f3 = ap[3];
        *(uint4*)awr0 = pack8(f0, f1);
        *(uint4*)awr1 = pack8(f2, f3);
        float4 g0, g1, g2, g3;
        if (vok) {
            const float4* bp = (const float4*)(bptr + kt * 32);
            g0 = bp[0]; g1 = bp[1]; g2 = bp[2]; g3 = bp[3];
        } else {
            g0 = g1 = g2 = g3 = make_float4(0.f, 0.f, 0.f, 0.f);
        }
        *(uint4*)bwr0 = pack8(g0, g1);
        *(uint4*)bwr1 = pack8(g2, g3);
        __syncthreads();
        short8 a[4];
        #pragma unroll
        for (int m = 0; m < 4; ++m) a[m] = *(const short8*)(As + a_off[m]);
        #pragma unroll
        for (int n = 0; n < 4; ++n) {
            short8 b = *(const short8*)(Bs + b_off[n]);
            #pragma unroll
            for (int m = 0; m < 4; ++m)
                acc[m][n] = __builtin_amdgcn_mfma_f32_16x16x32_bf16(a[m], b, acc[m][n], 0, 0, 0);
        }
    }

    #pragma unroll
    for (int m = 0; m < 4; ++m)
        #pragma unroll
        for (int r = 0; r < 4; ++r) {
            const int row = wm*64 + m*16 + lg*4 + r;
            #pragma unroll
            for (int n = 0; n < 4; ++n) {
                const int col = vbase + wn*64 + n*16 + li;
                if (col < VOCAB)
                    pred[(size_t)row * VOCAB + col] = acc[m][n][r] + fcb[col];
            }
        }
}

// ---------------------------------------------------------------------------
extern "C" void kernel_launch(void* const* d_in, const int* in_sizes, int n_in,
                              void* d_out, int out_size, void* d_ws, size_t ws_size,
                              hipStream_t stream)
{
    const int*   x      = (const int*)  d_in[0];
    const float* enc    = (const float*)d_in[1];
    const float* hidden = (const float*)d_in[2];
    const float* cell   = (const float*)d_in[3];
    const float* emb    = (const float*)d_in[4];
    const float* W_ih   = (const float*)d_in[5];
    const float* W_hh   = (const float*)d_in[6];
    const float* b_ih   = (const float*)d_in[7];
    const float* b_hh   = (const float*)d_in[8];
    const float* fc_w   = (const float*)d_in[9];
    const float* fc_b   = (const float*)d_in[10];
    const float* W1_w   = (const float*)d_in[11];
    const float* W1_b   = (const float*)d_in[12];
    const float* W2_w   = (const float*)d_in[13];
    const float* W2_b   = (const float*)d_in[14];
    const float* V_w    = (const float*)d_in[15];
    const float* V_b    = (const float*)d_in[16];

    float* out   = (float*)d_out;
    float* pred  = out;                                   // [128][50257]
    float* out_h = out + (size_t)BB * VOCAB;              // [128][256]
    float* out_c = out_h + BB * HID;                      // [128][256]
    float* attw  = out_c + BB * HID;                      // [128][2048]

    char* ws = (char*)d_ws;
    unsigned short* W1bf = (unsigned short*)ws;           // 131072 B
    float* qb  = (float*)(ws + 131072);                   // 131072 B
    float* e   = (float*)(ws + 262144);                   // 1 MiB
    float* ctx = (float*)(ws + 262144 + 1048576);         // 131072 B

    k_prep   <<<dim3(192),               dim3(256), 0, stream>>>(hidden, W2_w, W1_b, W2_b, W1_w, W1bf, qb);
    k_escore <<<dim3(1024),              dim3(512), 0, stream>>>(enc, W1bf, qb, V_w, V_b, e);
    k_softmax<<<dim3(BB),                dim3(256), 0, stream>>>(e, attw);
    hipMemsetAsync(ctx, 0, BB * HID * sizeof(float), stream);
    k_ctx    <<<dim3(BB * 8),            dim3(256), 0, stream>>>(enc, attw, ctx);
    k_lstm   <<<dim3(BB),                dim3(256), 0, stream>>>(ctx, x, emb, hidden, cell,
                                                                 W_ih, W_hh, b_ih, b_hh, out_h, out_c);
    k_fc     <<<dim3((VOCAB + 127)/128), dim3(256), 0, stream>>>(out_h, fc_w, fc_b, pred);
}